// Round 12
// baseline (578.481 us; speedup 1.0000x reference)
//
#include <hip/hip_runtime.h>
#include <hip/hip_cooperative_groups.h>
#include <math.h>

namespace cg = cooperative_groups;

#define NB   8
#define NC   1024
#define NL   4096
#define NCTX 768
#define EPSV 1e-5f
#define SCALEV 0.03125f   // 1024^-0.5
#define NBLK 1024

// workspace layout (float offsets) — shared by both paths (strides differ per path but
// writer/reader pairs are internally consistent within each path)
enum : int {
  OFF_KV    = 0,         // 8*2048 = 16384
  OFF_PV    = 16384,     // 8*1024 = 8192
  OFF_QP    = 24576,     // 64 oc * 8 b * 1024 c = 524288
  OFF_SPART = 548864,    // fused: 64 bz * 16*2 ; split: 64 bz * 32*2
  OFF_TPART = 552960,    // 64 bz * 2 cs * 4096 = 524288
  OFF_ATTN  = 1077248,   // 8*4096 = 32768
  OFF_S     = 1110016,   // 8
  WS_FLOATS = 1110032
};

__device__ __forceinline__ float wave_sum(float v) {
  #pragma unroll
  for (int off = 32; off > 0; off >>= 1) v += __shfl_xor(v, off, 64);
  return v;
}
__device__ __forceinline__ float breduce_sum(float v, float* red) {
  int t = threadIdx.x;
  red[t] = v; __syncthreads();
  for (int s = 128; s > 0; s >>= 1) { if (t < s) red[t] += red[t + s]; __syncthreads(); }
  float r = red[0]; __syncthreads();
  return r;
}

// ======================= PATH A: cooperative fused kernel =======================
__global__ __launch_bounds__(256, 4) void k_fused(
    const float* __restrict__ x,   const float* __restrict__ ctx,
    const float* __restrict__ gng, const float* __restrict__ lng,
    const float* __restrict__ lnb, const float* __restrict__ Wq,
    const float* __restrict__ Wkv, const float* __restrict__ bkv,
    const float* __restrict__ Wp,  const float* __restrict__ bp,
    float* __restrict__ ws,        float* __restrict__ out) {
  cg::grid_group gg = cg::this_grid();
  __shared__ __align__(16) char smem[32768];
  int t = threadIdx.x, bid = blockIdx.x;
  int wave = t >> 6, lane = t & 63;

  if (bid == 0 && t < NB) ws[OFF_S + t] = 0.f;

  // ---- P1: blocks [0,128): LN(ctx)+kv. blocks [128,1024): prefetch Wq/Wp ----
  if (bid < 128) {
    float* scf = (float*)smem;                     // 8*768 floats = 24 KB
    #pragma unroll
    for (int bb = 0; bb < 2; bb++) {
      int b = wave * 2 + bb;
      const float* row = ctx + b * NCTX;
      float v[12]; float s = 0.f;
      #pragma unroll
      for (int k = 0; k < 12; k++) { v[k] = row[lane + 64 * k]; s += v[k]; }
      float mu = wave_sum(s) * (1.0f / NCTX);
      float s2 = 0.f;
      #pragma unroll
      for (int k = 0; k < 12; k++) { float d = v[k] - mu; s2 = fmaf(d, d, s2); }
      float rstd = rsqrtf(wave_sum(s2) * (1.0f / NCTX) + EPSV);
      #pragma unroll
      for (int k = 0; k < 12; k++) {
        int j = lane + 64 * k;
        scf[b * NCTX + j] = (v[k] - mu) * rstd * lng[j] + lnb[j];
      }
    }
    __syncthreads();
    const float4* W4  = (const float4*)Wkv;
    const float4* sc4 = (const float4*)scf;
    #pragma unroll
    for (int rr = 0; rr < 4; rr++) {
      int j = bid * 16 + wave * 4 + rr;            // j < 2048 = Wkv rows
      float4 w0 = W4[(size_t)j * 192 + lane];
      float4 w1 = W4[(size_t)j * 192 + lane + 64];
      float4 w2 = W4[(size_t)j * 192 + lane + 128];
      #pragma unroll
      for (int b = 0; b < 8; b++) {
        const float4* sb = sc4 + b * 192;
        float4 c0 = sb[lane], c1 = sb[lane + 64], c2 = sb[lane + 128];
        float a = w0.x*c0.x + w0.y*c0.y + w0.z*c0.z + w0.w*c0.w
                + w1.x*c1.x + w1.y*c1.y + w1.z*c1.z + w1.w*c1.w
                + w2.x*c2.x + w2.y*c2.y + w2.z*c2.z + w2.w*c2.w;
        a = wave_sum(a);
        if (lane == 0) ws[OFF_KV + b * 2048 + j] = a + bkv[j];
      }
    }
  } else {
    const float4* Wq4 = (const float4*)Wq;
    const float4* Wp4 = (const float4*)Wp;
    int pid = bid - 128;                           // 896 blocks
    float acc = 0.f;
    for (int idx = pid * 256 + t; idx < 524288; idx += 896 * 256) {
      float4 v = (idx < 262144) ? Wq4[idx] : Wp4[idx - 262144];
      acc += v.x + v.y + v.z + v.w;
    }
    asm volatile("" :: "v"(acc));
  }
  gg.sync();

  // ---- P2: blocks [0,64): kq partials; [64,128): pv ----
  if (bid < 64) {
    float* sk = (float*)smem;                      // [8][16]
    if (t < 128) { int b = t >> 4, o = t & 15; sk[b * 16 + o] = ws[OFF_KV + b * 2048 + bid * 16 + o]; }
    __syncthreads();
    const float4* Wq4 = (const float4*)Wq;
    float4 acc[8];
    #pragma unroll
    for (int b = 0; b < 8; b++) acc[b] = make_float4(0.f, 0.f, 0.f, 0.f);
    int o0 = bid * 16;
    #pragma unroll 4
    for (int oi = 0; oi < 16; oi++) {
      float4 w = Wq4[(size_t)(o0 + oi) * 256 + t];
      #pragma unroll
      for (int b = 0; b < 8; b++) {
        float kk = sk[b * 16 + oi];
        acc[b].x = fmaf(kk, w.x, acc[b].x);
        acc[b].y = fmaf(kk, w.y, acc[b].y);
        acc[b].z = fmaf(kk, w.z, acc[b].z);
        acc[b].w = fmaf(kk, w.w, acc[b].w);
      }
    }
    float4* qp4 = (float4*)(ws + OFF_QP);
    #pragma unroll
    for (int b = 0; b < 8; b++) qp4[(bid * 8 + b) * 256 + t] = acc[b];
  } else if (bid < 128) {
    float4* sbuf = (float4*)smem;                  // [8][256] = 32 KB
    const float4* kv4 = (const float4*)(ws + OFF_KV);
    #pragma unroll
    for (int rep = 0; rep < 8; rep++) {
      int idx = rep * 256 + t;
      int b = idx >> 8, i = idx & 255;
      sbuf[idx] = kv4[b * 512 + 256 + i];          // v half
    }
    __syncthreads();
    const float4* Wp4 = (const float4*)Wp;
    #pragma unroll
    for (int rr = 0; rr < 4; rr++) {
      int o = (bid - 64) * 16 + wave * 4 + rr;     // o < 1024 = Wp rows
      float4 w0 = Wp4[(size_t)o * 256 + lane];
      float4 w1 = Wp4[(size_t)o * 256 + lane + 64];
      float4 w2 = Wp4[(size_t)o * 256 + lane + 128];
      float4 w3 = Wp4[(size_t)o * 256 + lane + 192];
      #pragma unroll
      for (int b = 0; b < 8; b++) {
        const float4* sb = sbuf + b * 256;
        float4 c0 = sb[lane], c1 = sb[lane + 64], c2 = sb[lane + 128], c3 = sb[lane + 192];
        float a = w0.x*c0.x + w0.y*c0.y + w0.z*c0.z + w0.w*c0.w
                + w1.x*c1.x + w1.y*c1.y + w1.z*c1.z + w1.w*c1.w
                + w2.x*c2.x + w2.y*c2.y + w2.z*c2.z + w2.w*c2.w
                + w3.x*c3.x + w3.y*c3.y + w3.z*c3.z + w3.w*c3.w;
        a = wave_sum(a);
        if (lane == 0) ws[OFF_PV + b * NC + o] = a;
      }
    }
  }
  gg.sync();

  // ---- P3: all 1024 blocks — stream x: GN stats + score partial dots ----
  {
    float*  red  = (float*)smem;
    float*  sw   = (float*)(smem + 1024);
    float4* part = (float4*)(smem + 1280);
    int lc = bid & 7, cs = (bid >> 3) & 1, bz = bid >> 4;   // bz = b*8+g
    int b = bz >> 3, g = bz & 7;
    int c0 = g * 128 + cs * 64;
    {
      int cl = t & 63, sp = t >> 6;
      const float* qp = ws + OFF_QP + b * 1024 + c0 + cl;
      float s = 0.f;
      #pragma unroll 4
      for (int oc = sp * 16; oc < sp * 16 + 16; oc++) s += qp[(size_t)oc * 8192];
      red[t] = s;
      __syncthreads();
      if (t < 64) sw[t] = gng[c0 + t] * ((red[t] + red[t + 64]) + (red[t + 128] + red[t + 192]));
      __syncthreads();
    }
    int tl = t & 63, q = t >> 6;
    const float4* x4 = (const float4*)x;
    float s1 = 0.f, s2 = 0.f;
    #pragma unroll
    for (int sub = 0; sub < 2; sub++) {
      int l4 = lc * 128 + sub * 64 + tl;
      float4 tacc = make_float4(0.f, 0.f, 0.f, 0.f);
      #pragma unroll 4
      for (int ci = q * 16; ci < q * 16 + 16; ci++) {
        float w = sw[ci];
        float4 v = x4[(size_t)(b * NC + c0 + ci) * 1024 + l4];
        tacc.x = fmaf(w, v.x, tacc.x);
        tacc.y = fmaf(w, v.y, tacc.y);
        tacc.z = fmaf(w, v.z, tacc.z);
        tacc.w = fmaf(w, v.w, tacc.w);
        s1 += (v.x + v.y) + (v.z + v.w);
        s2 = fmaf(v.x, v.x, s2); s2 = fmaf(v.y, v.y, s2);
        s2 = fmaf(v.z, v.z, s2); s2 = fmaf(v.w, v.w, s2);
      }
      if (q > 0) part[(q - 1) * 64 + tl] = tacc;
      __syncthreads();
      if (q == 0) {
        float4 p0 = part[tl], p1 = part[64 + tl], p2 = part[128 + tl];
        tacc.x += (p0.x + p1.x) + p2.x;
        tacc.y += (p0.y + p1.y) + p2.y;
        tacc.z += (p0.z + p1.z) + p2.z;
        tacc.w += (p0.w + p1.w) + p2.w;
        ((float4*)(ws + OFF_TPART))[(size_t)(bz * 2 + cs) * 1024 + l4] = tacc;
      }
      __syncthreads();
    }
    float S1 = breduce_sum(s1, red);
    float S2 = breduce_sum(s2, red);
    if (t == 0) {
      float* sp = ws + OFF_SPART + (bz * 16 + cs * 8 + lc) * 2;
      sp[0] = S1; sp[1] = S2;
    }
  }
  gg.sync();

  // ---- P4: blocks [0,64): scores -> exp + partial sums ----
  if (bid < 64) {
    float* srstd = (float*)smem;
    float* red   = (float*)(smem + 1024);
    int lc8 = bid & 7, b = bid >> 3;
    if (t < 8) {
      const float* sp = ws + OFF_SPART + (b * 8 + t) * 32;
      float S1 = 0.f, S2 = 0.f;
      #pragma unroll
      for (int i = 0; i < 16; i++) { S1 += sp[i * 2]; S2 += sp[i * 2 + 1]; }
      const float invN = 1.0f / (128.0f * (float)NL);
      float mu = S1 * invN;
      float var = S2 * invN - mu * mu;
      srstd[t] = rsqrtf(var + EPSV);
    }
    __syncthreads();
    float esum = 0.f;
    #pragma unroll
    for (int r = 0; r < 2; r++) {
      int l = lc8 * 512 + r * 256 + t;
      float acc = 0.f;
      #pragma unroll
      for (int g = 0; g < 8; g++) {
        const float* tg = ws + OFF_TPART + (size_t)(b * 8 + g) * 8192;
        acc = fmaf(srstd[g], tg[l] + tg[4096 + l], acc);
      }
      float e = expf(fminf(SCALEV * acc, 60.0f));
      ws[OFF_ATTN + b * NL + l] = e;
      esum += e;
    }
    float tot = breduce_sum(esum, red);
    if (t == 0) atomicAdd(ws + OFF_S + b, tot);
  }
  gg.sync();

  // ---- P5: all blocks — out = x + e*(pv/S) + bp ----
  {
    const float4* x4 = (const float4*)x;
    float4* o4 = (float4*)out;
    const float4* a4 = (const float4*)(ws + OFF_ATTN);
    const float* pv = ws + OFF_PV;
    const float* Ss = ws + OFF_S;
    const size_t NT4 = (size_t)NB * NC * NL / 4;
    for (size_t i = (size_t)bid * 256 + t; i < NT4; i += (size_t)NBLK * 256) {
      int b  = (int)(i >> 20);
      int c  = (int)((i >> 10) & (NC - 1));
      int l4 = (int)(i & 1023);
      float4 xv = x4[i];
      float4 av = a4[(size_t)b * 1024 + l4];
      float p  = pv[b * NC + c] / Ss[b];
      float bb = bp[c];
      float4 r;
      r.x = xv.x + fmaf(av.x, p, bb);
      r.y = xv.y + fmaf(av.y, p, bb);
      r.z = xv.z + fmaf(av.z, p, bb);
      r.w = xv.w + fmaf(av.w, p, bb);
      o4[i] = r;
    }
  }
}

// ======================= PATH B: verified split kernels (R8) =======================
__global__ void k_kv(const float* __restrict__ ctx, const float* __restrict__ lng,
                     const float* __restrict__ lnb, const float* __restrict__ Wkv,
                     const float* __restrict__ bkv, float* __restrict__ ws) {
  __shared__ __align__(16) float scf[8 * NCTX];
  int t = threadIdx.x, bid = blockIdx.x;
  int wave = t >> 6, lane = t & 63;
  if (bid == 0 && t < NB) ws[OFF_S + t] = 0.f;
  #pragma unroll
  for (int bb = 0; bb < 2; bb++) {
    int b = wave * 2 + bb;
    const float* row = ctx + b * NCTX;
    float v[12];
    float s = 0.f;
    #pragma unroll
    for (int k = 0; k < 12; k++) { v[k] = row[lane + 64 * k]; s += v[k]; }
    float mu = wave_sum(s) * (1.0f / NCTX);
    float s2 = 0.f;
    #pragma unroll
    for (int k = 0; k < 12; k++) { float d = v[k] - mu; s2 = fmaf(d, d, s2); }
    float rstd = rsqrtf(wave_sum(s2) * (1.0f / NCTX) + EPSV);
    #pragma unroll
    for (int k = 0; k < 12; k++) {
      int j = lane + 64 * k;
      scf[b * NCTX + j] = (v[k] - mu) * rstd * lng[j] + lnb[j];
    }
  }
  __syncthreads();
  const float4* W4 = reinterpret_cast<const float4*>(Wkv);
  const float4* sc4 = reinterpret_cast<const float4*>(scf);
  #pragma unroll
  for (int rr = 0; rr < 4; rr++) {
    int j = bid * 16 + wave * 4 + rr;
    float4 wv0 = W4[(size_t)j * 192 + lane];
    float4 wv1 = W4[(size_t)j * 192 + lane + 64];
    float4 wv2 = W4[(size_t)j * 192 + lane + 128];
    #pragma unroll
    for (int b = 0; b < 8; b++) {
      const float4* sb = sc4 + b * 192;
      float4 c0 = sb[lane], c1 = sb[lane + 64], c2 = sb[lane + 128];
      float a = wv0.x*c0.x + wv0.y*c0.y + wv0.z*c0.z + wv0.w*c0.w
              + wv1.x*c1.x + wv1.y*c1.y + wv1.z*c1.z + wv1.w*c1.w
              + wv2.x*c2.x + wv2.y*c2.y + wv2.z*c2.z + wv2.w*c2.w;
      a = wave_sum(a);
      if (lane == 0) ws[OFF_KV + b * 2048 + j] = a + bkv[j];
    }
  }
}

__global__ void k_mv(const float* __restrict__ Wq, const float* __restrict__ Wp,
                     float* __restrict__ ws) {
  __shared__ float4 sbuf[8 * 256];
  int t = threadIdx.x, bid = blockIdx.x;
  if (bid < 64) {
    float* sk = reinterpret_cast<float*>(sbuf);
    if (t < 128) { int b = t >> 4, o = t & 15; sk[b * 16 + o] = ws[OFF_KV + b * 2048 + bid * 16 + o]; }
    __syncthreads();
    const float4* Wq4 = reinterpret_cast<const float4*>(Wq);
    float4 acc[8];
    #pragma unroll
    for (int b = 0; b < 8; b++) acc[b] = make_float4(0.f, 0.f, 0.f, 0.f);
    int o0 = bid * 16;
    #pragma unroll 4
    for (int oi = 0; oi < 16; oi++) {
      float4 w = Wq4[(size_t)(o0 + oi) * 256 + t];
      #pragma unroll
      for (int b = 0; b < 8; b++) {
        float kk = sk[b * 16 + oi];
        acc[b].x = fmaf(kk, w.x, acc[b].x);
        acc[b].y = fmaf(kk, w.y, acc[b].y);
        acc[b].z = fmaf(kk, w.z, acc[b].z);
        acc[b].w = fmaf(kk, w.w, acc[b].w);
      }
    }
    float4* qp4 = reinterpret_cast<float4*>(ws + OFF_QP);
    #pragma unroll
    for (int b = 0; b < 8; b++) qp4[(bid * 8 + b) * 256 + t] = acc[b];
  } else {
    const float4* kv4 = reinterpret_cast<const float4*>(ws + OFF_KV);
    #pragma unroll
    for (int rep = 0; rep < 8; rep++) {
      int idx = rep * 256 + t;
      int b = idx >> 8, i = idx & 255;
      sbuf[idx] = kv4[b * 512 + 256 + i];
    }
    __syncthreads();
    int wave = t >> 6, lane = t & 63;
    const float4* Wp4 = reinterpret_cast<const float4*>(Wp);
    #pragma unroll
    for (int rr = 0; rr < 4; rr++) {
      int o = (bid - 64) * 16 + wave * 4 + rr;
      float4 wv0 = Wp4[(size_t)o * 256 + lane];
      float4 wv1 = Wp4[(size_t)o * 256 + lane + 64];
      float4 wv2 = Wp4[(size_t)o * 256 + lane + 128];
      float4 wv3 = Wp4[(size_t)o * 256 + lane + 192];
      #pragma unroll
      for (int b = 0; b < 8; b++) {
        const float4* sb = sbuf + b * 256;
        float4 c0 = sb[lane], c1 = sb[lane + 64], c2 = sb[lane + 128], c3 = sb[lane + 192];
        float a = wv0.x*c0.x + wv0.y*c0.y + wv0.z*c0.z + wv0.w*c0.w
                + wv1.x*c1.x + wv1.y*c1.y + wv1.z*c1.z + wv1.w*c1.w
                + wv2.x*c2.x + wv2.y*c2.y + wv2.z*c2.z + wv2.w*c2.w
                + wv3.x*c3.x + wv3.y*c3.y + wv3.z*c3.z + wv3.w*c3.w;
        a = wave_sum(a);
        if (lane == 0) ws[OFF_PV + b * NC + o] = a;
      }
    }
  }
}

// split pass1: grid (16,2,64), SPART stride 32 per bz
__global__ void k_pass1(const float* __restrict__ x, const float* __restrict__ gng,
                        float* __restrict__ ws) {
  __shared__ float red[256];
  __shared__ float sw[64];
  __shared__ __align__(16) float4 part[192];
  int t  = threadIdx.x;
  int lc = blockIdx.x;
  int cs = blockIdx.y;
  int bz = blockIdx.z;
  int b = bz >> 3, g = bz & 7;
  int c0 = g * 128 + cs * 64;
  {
    int cl = t & 63, sp = t >> 6;
    const float* qp = ws + OFF_QP + b * 1024 + c0 + cl;
    float s = 0.f;
    #pragma unroll 4
    for (int oc = sp * 16; oc < sp * 16 + 16; oc++) s += qp[(size_t)oc * 8192];
    red[t] = s;
    __syncthreads();
    if (t < 64) sw[t] = gng[c0 + t] * ((red[t] + red[t + 64]) + (red[t + 128] + red[t + 192]));
    __syncthreads();
  }
  int tl = t & 63, q = t >> 6;
  int l4 = lc * 64 + tl;
  const float4* x4 = reinterpret_cast<const float4*>(x);
  float4 tacc = make_float4(0.f, 0.f, 0.f, 0.f);
  float s1 = 0.f, s2 = 0.f;
  #pragma unroll 4
  for (int ci = q * 16; ci < q * 16 + 16; ci++) {
    float w = sw[ci];
    float4 v = x4[(size_t)(b * NC + c0 + ci) * 1024 + l4];
    tacc.x = fmaf(w, v.x, tacc.x);
    tacc.y = fmaf(w, v.y, tacc.y);
    tacc.z = fmaf(w, v.z, tacc.z);
    tacc.w = fmaf(w, v.w, tacc.w);
    s1 += (v.x + v.y) + (v.z + v.w);
    s2 = fmaf(v.x, v.x, s2); s2 = fmaf(v.y, v.y, s2);
    s2 = fmaf(v.z, v.z, s2); s2 = fmaf(v.w, v.w, s2);
  }
  if (q > 0) part[(q - 1) * 64 + tl] = tacc;
  __syncthreads();
  if (q == 0) {
    float4 p0 = part[tl], p1 = part[64 + tl], p2 = part[128 + tl];
    tacc.x += (p0.x + p1.x) + p2.x;
    tacc.y += (p0.y + p1.y) + p2.y;
    tacc.z += (p0.z + p1.z) + p2.z;
    tacc.w += (p0.w + p1.w) + p2.w;
    reinterpret_cast<float4*>(ws + OFF_TPART)[(size_t)(bz * 2 + cs) * 1024 + l4] = tacc;
  }
  float S1 = breduce_sum(s1, red);
  float S2 = breduce_sum(s2, red);
  if (t == 0) {
    float* sp = ws + OFF_SPART + (bz * 32 + cs * 16 + lc) * 2;
    sp[0] = S1; sp[1] = S2;
  }
}

__global__ void k_scores(float* __restrict__ ws) {
  __shared__ float srstd[8];
  __shared__ float red[256];
  int t = threadIdx.x, lc = blockIdx.x, b = blockIdx.y;
  if (t < 8) {
    const float* sp = ws + OFF_SPART + (b * 8 + t) * 64;
    float S1 = 0.f, S2 = 0.f;
    #pragma unroll
    for (int i = 0; i < 32; i++) { S1 += sp[i * 2]; S2 += sp[i * 2 + 1]; }
    const float invN = 1.0f / (128.0f * (float)NL);
    float mu = S1 * invN;
    float var = S2 * invN - mu * mu;
    srstd[t] = rsqrtf(var + EPSV);
  }
  __syncthreads();
  float esum = 0.f;
  #pragma unroll
  for (int r = 0; r < 2; r++) {
    int l = lc * 512 + r * 256 + t;
    float acc = 0.f;
    #pragma unroll
    for (int g = 0; g < 8; g++) {
      const float* tg = ws + OFF_TPART + (size_t)(b * 8 + g) * 8192;
      acc = fmaf(srstd[g], tg[l] + tg[4096 + l], acc);
    }
    float e = expf(fminf(SCALEV * acc, 60.0f));
    ws[OFF_ATTN + b * NL + l] = e;
    esum += e;
  }
  float tot = breduce_sum(esum, red);
  if (t == 0) atomicAdd(ws + OFF_S + b, tot);
}

__global__ void k_out(const float* __restrict__ x, const float* __restrict__ bp,
                      const float* __restrict__ ws, float* __restrict__ out) {
  const float4* x4 = reinterpret_cast<const float4*>(x);
  float4* o4 = reinterpret_cast<float4*>(out);
  const float4* a4 = reinterpret_cast<const float4*>(ws + OFF_ATTN);
  const float* pv = ws + OFF_PV;
  const float* Ss = ws + OFF_S;
  const size_t NT4 = (size_t)NB * NC * NL / 4;
  for (size_t i = (size_t)blockIdx.x * blockDim.x + threadIdx.x; i < NT4;
       i += (size_t)gridDim.x * blockDim.x) {
    int b  = (int)(i >> 20);
    int c  = (int)((i >> 10) & (NC - 1));
    int l4 = (int)(i & 1023);
    float4 xv = x4[i];
    float4 av = a4[(size_t)b * 1024 + l4];
    float p  = pv[b * NC + c] / Ss[b];
    float bb = bp[c];
    float4 r;
    r.x = xv.x + fmaf(av.x, p, bb);
    r.y = xv.y + fmaf(av.y, p, bb);
    r.z = xv.z + fmaf(av.z, p, bb);
    r.w = xv.w + fmaf(av.w, p, bb);
    o4[i] = r;
  }
}

extern "C" void kernel_launch(void* const* d_in, const int* in_sizes, int n_in,
                              void* d_out, int out_size, void* d_ws, size_t ws_size,
                              hipStream_t stream) {
  const float* x    = (const float*)d_in[0];
  const float* ctx  = (const float*)d_in[1];
  const float* gng  = (const float*)d_in[2];
  // d_in[3] = gn_beta, d_in[7] = bq : per-b constants, cancel under softmax
  const float* lng  = (const float*)d_in[4];
  const float* lnb  = (const float*)d_in[5];
  const float* Wq   = (const float*)d_in[6];
  const float* Wkv  = (const float*)d_in[8];
  const float* bkv  = (const float*)d_in[9];
  const float* Wp   = (const float*)d_in[10];
  const float* bp   = (const float*)d_in[11];
  float* ws  = (float*)d_ws;
  float* out = (float*)d_out;

  void* args[] = { (void*)&x, (void*)&ctx, (void*)&gng, (void*)&lng, (void*)&lnb,
                   (void*)&Wq, (void*)&Wkv, (void*)&bkv, (void*)&Wp, (void*)&bp,
                   (void*)&ws, (void*)&out };
  hipError_t err = hipLaunchCooperativeKernel((void*)k_fused, dim3(NBLK), dim3(256),
                                              args, 0, stream);
  if (err != hipSuccess) {
    // fallback: verified split path (deterministic: same decision every call)
    hipLaunchKernelGGL(k_kv,     dim3(128),        dim3(256), 0, stream, ctx, lng, lnb, Wkv, bkv, ws);
    hipLaunchKernelGGL(k_mv,     dim3(128),        dim3(256), 0, stream, Wq, Wp, ws);
    hipLaunchKernelGGL(k_pass1,  dim3(16, 2, 64),  dim3(256), 0, stream, x, gng, ws);
    hipLaunchKernelGGL(k_scores, dim3(8, 8),       dim3(256), 0, stream, ws);
    hipLaunchKernelGGL(k_out,    dim3(2048),       dim3(256), 0, stream, x, bp, ws, out);
  }
}

// Round 15
// 101.248 us; speedup vs baseline: 5.7135x; 5.7135x over previous
//
#include <hip/hip_runtime.h>
#include <math.h>

#define NB   8
#define NC   1024
#define NL   4096
#define NCTX 768
#define EPSV 1e-5f
#define SCALEV 0.03125f   // 1024^-0.5

typedef float floatx4 __attribute__((ext_vector_type(4)));   // NT-store-compatible

// workspace layout (float offsets)
enum : int {
  OFF_KV    = 0,         // 8*2048 = 16384
  OFF_PV    = 16384,     // 8*1024 = 8192
  OFF_QP    = 24576,     // 64 oc * 8 b * 1024 c = 524288
  OFF_SPART = 548864,    // 64 bz * 32 * 2 = 4096
  OFF_TPART = 552960,    // 64 bz * 2 cs * 4096 = 524288
  OFF_ATTN  = 1077248,   // 8*4096 = 32768
  OFF_S     = 1110016,   // 8
  WS_FLOATS = 1110024
};

__device__ __forceinline__ float breduce_sum(float v, float* red) {
  int t = threadIdx.x;
  red[t] = v; __syncthreads();
  for (int s = 128; s > 0; s >>= 1) { if (t < s) red[t] += red[t + s]; __syncthreads(); }
  float r = red[0]; __syncthreads();
  return r;
}
__device__ __forceinline__ float wave_sum(float v) {
  #pragma unroll
  for (int off = 32; off > 0; off >>= 1) v += __shfl_xor(v, off, 64);
  return v;
}

// ---------------- K1: LN(context) in-LDS + kv = ctxn @ Wkv^T + bkv ----------------
__global__ void k_kv(const float* __restrict__ ctx, const float* __restrict__ lng,
                     const float* __restrict__ lnb, const float* __restrict__ Wkv,
                     const float* __restrict__ bkv, float* __restrict__ ws) {
  __shared__ __align__(16) float scf[8 * NCTX];   // 24 KB
  int t = threadIdx.x, bid = blockIdx.x;
  int wave = t >> 6, lane = t & 63;
  if (bid == 0 && t < NB) ws[OFF_S + t] = 0.f;    // zero softmax sums for k_scores
  #pragma unroll
  for (int bb = 0; bb < 2; bb++) {
    int b = wave * 2 + bb;
    const float* row = ctx + b * NCTX;
    float v[12];
    float s = 0.f;
    #pragma unroll
    for (int k = 0; k < 12; k++) { v[k] = row[lane + 64 * k]; s += v[k]; }
    float mu = wave_sum(s) * (1.0f / NCTX);
    float s2 = 0.f;
    #pragma unroll
    for (int k = 0; k < 12; k++) { float d = v[k] - mu; s2 = fmaf(d, d, s2); }
    float rstd = rsqrtf(wave_sum(s2) * (1.0f / NCTX) + EPSV);
    #pragma unroll
    for (int k = 0; k < 12; k++) {
      int j = lane + 64 * k;
      scf[b * NCTX + j] = (v[k] - mu) * rstd * lng[j] + lnb[j];
    }
  }
  __syncthreads();
  const float4* W4 = reinterpret_cast<const float4*>(Wkv);
  const float4* sc4 = reinterpret_cast<const float4*>(scf);
  #pragma unroll
  for (int rr = 0; rr < 4; rr++) {
    int j = bid * 16 + wave * 4 + rr;
    float4 wv0 = W4[(size_t)j * 192 + lane];
    float4 wv1 = W4[(size_t)j * 192 + lane + 64];
    float4 wv2 = W4[(size_t)j * 192 + lane + 128];
    #pragma unroll
    for (int b = 0; b < 8; b++) {
      const float4* sb = sc4 + b * 192;
      float4 c0 = sb[lane], c1 = sb[lane + 64], c2 = sb[lane + 128];
      float a = wv0.x*c0.x + wv0.y*c0.y + wv0.z*c0.z + wv0.w*c0.w
              + wv1.x*c1.x + wv1.y*c1.y + wv1.z*c1.z + wv1.w*c1.w
              + wv2.x*c2.x + wv2.y*c2.y + wv2.z*c2.z + wv2.w*c2.w;
      a = wave_sum(a);
      if (lane == 0) ws[OFF_KV + b * 2048 + j] = a + bkv[j];
    }
  }
}

// ---------------- K2: kq partials (split-K) + pv (wave-per-row) ----------------
__global__ void k_mv(const float* __restrict__ Wq, const float* __restrict__ Wp,
                     float* __restrict__ ws) {
  __shared__ float4 sbuf[8 * 256];      // 32 KB, dual-use
  int t = threadIdx.x, bid = blockIdx.x;
  if (bid < 64) {
    float* sk = reinterpret_cast<float*>(sbuf);   // sk[8][16]
    if (t < 128) { int b = t >> 4, o = t & 15; sk[b * 16 + o] = ws[OFF_KV + b * 2048 + bid * 16 + o]; }
    __syncthreads();
    const float4* Wq4 = reinterpret_cast<const float4*>(Wq);
    float4 acc[8];
    #pragma unroll
    for (int b = 0; b < 8; b++) acc[b] = make_float4(0.f, 0.f, 0.f, 0.f);
    int o0 = bid * 16;
    #pragma unroll 4
    for (int oi = 0; oi < 16; oi++) {
      float4 w = Wq4[(size_t)(o0 + oi) * 256 + t];
      #pragma unroll
      for (int b = 0; b < 8; b++) {
        float kk = sk[b * 16 + oi];
        acc[b].x = fmaf(kk, w.x, acc[b].x);
        acc[b].y = fmaf(kk, w.y, acc[b].y);
        acc[b].z = fmaf(kk, w.z, acc[b].z);
        acc[b].w = fmaf(kk, w.w, acc[b].w);
      }
    }
    float4* qp4 = reinterpret_cast<float4*>(ws + OFF_QP);
    #pragma unroll
    for (int b = 0; b < 8; b++) qp4[(bid * 8 + b) * 256 + t] = acc[b];
  } else {
    const float4* kv4 = reinterpret_cast<const float4*>(ws + OFF_KV);
    #pragma unroll
    for (int rep = 0; rep < 8; rep++) {
      int idx = rep * 256 + t;            // idx < 2048
      int b = idx >> 8, i = idx & 255;
      sbuf[idx] = kv4[b * 512 + 256 + i]; // v half
    }
    __syncthreads();
    int wave = t >> 6, lane = t & 63;
    const float4* Wp4 = reinterpret_cast<const float4*>(Wp);
    #pragma unroll
    for (int rr = 0; rr < 4; rr++) {
      int o = (bid - 64) * 16 + wave * 4 + rr;
      float4 wv0 = Wp4[(size_t)o * 256 + lane];
      float4 wv1 = Wp4[(size_t)o * 256 + lane + 64];
      float4 wv2 = Wp4[(size_t)o * 256 + lane + 128];
      float4 wv3 = Wp4[(size_t)o * 256 + lane + 192];
      #pragma unroll
      for (int b = 0; b < 8; b++) {
        const float4* sb = sbuf + b * 256;
        float4 c0 = sb[lane], c1 = sb[lane + 64], c2 = sb[lane + 128], c3 = sb[lane + 192];
        float a = wv0.x*c0.x + wv0.y*c0.y + wv0.z*c0.z + wv0.w*c0.w
                + wv1.x*c1.x + wv1.y*c1.y + wv1.z*c1.z + wv1.w*c1.w
                + wv2.x*c2.x + wv2.y*c2.y + wv2.z*c2.z + wv2.w*c2.w
                + wv3.x*c3.x + wv3.y*c3.y + wv3.z*c3.z + wv3.w*c3.w;
        a = wave_sum(a);
        if (lane == 0) ws[OFF_PV + b * NC + o] = a;
      }
    }
  }
}

// ---------------- K3: stream x — GN stats + score partial dots ----------------
// grid (lc=16, cs=2, bz=64), block 256: 2048 blocks.
__global__ void k_pass1(const float* __restrict__ x, const float* __restrict__ gng,
                        float* __restrict__ ws) {
  __shared__ float red[256];
  __shared__ float sw[64];
  __shared__ __align__(16) float4 part[192];
  int t  = threadIdx.x;
  int lc = blockIdx.x;          // 0..15
  int cs = blockIdx.y;          // 0..1
  int bz = blockIdx.z;          // b*8+g
  int b = bz >> 3, g = bz & 7;
  int c0 = g * 128 + cs * 64;
  // combine 64 kq o-chunk partials -> wcoef for our 64 channels
  {
    int cl = t & 63, sp = t >> 6;
    const float* qp = ws + OFF_QP + b * 1024 + c0 + cl;
    float s = 0.f;
    #pragma unroll 4
    for (int oc = sp * 16; oc < sp * 16 + 16; oc++) s += qp[(size_t)oc * 8192];
    red[t] = s;
    __syncthreads();
    if (t < 64) sw[t] = gng[c0 + t] * ((red[t] + red[t + 64]) + (red[t + 128] + red[t + 192]));
    __syncthreads();
  }
  int tl = t & 63, q = t >> 6;
  int l4 = lc * 64 + tl;
  const float4* x4 = reinterpret_cast<const float4*>(x);
  float4 tacc = make_float4(0.f, 0.f, 0.f, 0.f);
  float s1 = 0.f, s2 = 0.f;
  #pragma unroll 4
  for (int ci = q * 16; ci < q * 16 + 16; ci++) {
    float w = sw[ci];
    float4 v = x4[(size_t)(b * NC + c0 + ci) * 1024 + l4];
    tacc.x = fmaf(w, v.x, tacc.x);
    tacc.y = fmaf(w, v.y, tacc.y);
    tacc.z = fmaf(w, v.z, tacc.z);
    tacc.w = fmaf(w, v.w, tacc.w);
    s1 += (v.x + v.y) + (v.z + v.w);
    s2 = fmaf(v.x, v.x, s2); s2 = fmaf(v.y, v.y, s2);
    s2 = fmaf(v.z, v.z, s2); s2 = fmaf(v.w, v.w, s2);
  }
  if (q > 0) part[(q - 1) * 64 + tl] = tacc;
  __syncthreads();
  if (q == 0) {
    float4 p0 = part[tl], p1 = part[64 + tl], p2 = part[128 + tl];
    tacc.x += (p0.x + p1.x) + p2.x;
    tacc.y += (p0.y + p1.y) + p2.y;
    tacc.z += (p0.z + p1.z) + p2.z;
    tacc.w += (p0.w + p1.w) + p2.w;
    reinterpret_cast<float4*>(ws + OFF_TPART)[(size_t)(bz * 2 + cs) * 1024 + l4] = tacc;
  }
  float S1 = breduce_sum(s1, red);
  float S2 = breduce_sum(s2, red);
  if (t == 0) {
    float* sp = ws + OFF_SPART + (bz * 32 + cs * 16 + lc) * 2;
    sp[0] = S1; sp[1] = S2;
  }
}

// ---------------- K4: scores -> exp (no global max; scores bounded) ----------------
__global__ void k_scores(float* __restrict__ ws) {
  __shared__ float srstd[8];
  __shared__ float red[256];
  int t = threadIdx.x, lc = blockIdx.x, b = blockIdx.y;
  if (t < 8) {
    const float* sp = ws + OFF_SPART + (b * 8 + t) * 64;
    float S1 = 0.f, S2 = 0.f;
    #pragma unroll
    for (int i = 0; i < 32; i++) { S1 += sp[i * 2]; S2 += sp[i * 2 + 1]; }
    const float invN = 1.0f / (128.0f * (float)NL);
    float mu = S1 * invN;
    float var = S2 * invN - mu * mu;
    srstd[t] = rsqrtf(var + EPSV);
  }
  __syncthreads();
  float esum = 0.f;
  #pragma unroll
  for (int r = 0; r < 2; r++) {
    int l = lc * 512 + r * 256 + t;
    float acc = 0.f;
    #pragma unroll
    for (int g = 0; g < 8; g++) {
      const float* tg = ws + OFF_TPART + (size_t)(b * 8 + g) * 8192;
      acc = fmaf(srstd[g], tg[l] + tg[4096 + l], acc);
    }
    float e = expf(fminf(SCALEV * acc, 60.0f));  // per-b consts cancel under softmax
    ws[OFF_ATTN + b * NL + l] = e;
    esum += e;
  }
  float tot = breduce_sum(esum, red);
  if (t == 0) atomicAdd(ws + OFF_S + b, tot);
}

// ---------------- K5: out = x + e*(pv/S) + bp  (NT stores: keep x in L3) ----------------
__global__ void k_out(const float* __restrict__ x, const float* __restrict__ bp,
                      const float* __restrict__ ws, float* __restrict__ out) {
  const float4* x4 = reinterpret_cast<const float4*>(x);
  floatx4* o4 = reinterpret_cast<floatx4*>(out);
  const float4* a4 = reinterpret_cast<const float4*>(ws + OFF_ATTN);
  const float* pv = ws + OFF_PV;
  const float* Ss = ws + OFF_S;
  const size_t NT4 = (size_t)NB * NC * NL / 4;  // 8388608
  for (size_t i = (size_t)blockIdx.x * blockDim.x + threadIdx.x; i < NT4;
       i += (size_t)gridDim.x * blockDim.x) {
    int b  = (int)(i >> 20);
    int c  = (int)((i >> 10) & (NC - 1));
    int l4 = (int)(i & 1023);
    float4 xv = x4[i];
    float4 av = a4[(size_t)b * 1024 + l4];
    float p  = pv[b * NC + c] / Ss[b];
    float bb = bp[c];
    floatx4 r;
    r.x = xv.x + fmaf(av.x, p, bb);
    r.y = xv.y + fmaf(av.y, p, bb);
    r.z = xv.z + fmaf(av.z, p, bb);
    r.w = xv.w + fmaf(av.w, p, bb);
    __builtin_nontemporal_store(r, &o4[i]);   // don't allocate out in cache; x stays L3-hot
  }
}

extern "C" void kernel_launch(void* const* d_in, const int* in_sizes, int n_in,
                              void* d_out, int out_size, void* d_ws, size_t ws_size,
                              hipStream_t stream) {
  const float* x    = (const float*)d_in[0];
  const float* ctx  = (const float*)d_in[1];
  const float* gng  = (const float*)d_in[2];
  // d_in[3] = gn_beta, d_in[7] = bq : per-b constants, cancel under softmax
  const float* lng  = (const float*)d_in[4];
  const float* lnb  = (const float*)d_in[5];
  const float* Wq   = (const float*)d_in[6];
  const float* Wkv  = (const float*)d_in[8];
  const float* bkv  = (const float*)d_in[9];
  const float* Wp   = (const float*)d_in[10];
  const float* bp   = (const float*)d_in[11];
  float* ws  = (float*)d_ws;
  float* out = (float*)d_out;

  hipLaunchKernelGGL(k_kv,     dim3(128),        dim3(256), 0, stream, ctx, lng, lnb, Wkv, bkv, ws);
  hipLaunchKernelGGL(k_mv,     dim3(128),        dim3(256), 0, stream, Wq, Wp, ws);
  hipLaunchKernelGGL(k_pass1,  dim3(16, 2, 64),  dim3(256), 0, stream, x, gng, ws);
  hipLaunchKernelGGL(k_scores, dim3(8, 8),       dim3(256), 0, stream, ws);
  hipLaunchKernelGGL(k_out,    dim3(2048),       dim3(256), 0, stream, x, bp, ws, out);
}

// Round 16
// 94.858 us; speedup vs baseline: 6.0984x; 1.0674x over previous
//
#include <hip/hip_runtime.h>
#include <math.h>

#define NB   8
#define NC   1024
#define NL   4096
#define NCTX 768
#define EPSV 1e-5f
#define SCALEV 0.03125f   // 1024^-0.5

typedef float floatx4 __attribute__((ext_vector_type(4)));   // NT-store-compatible

// workspace layout (float offsets)
enum : int {
  OFF_KV    = 0,         // 8*2048 = 16384
  OFF_PV    = 16384,     // 8*1024 = 8192
  OFF_QP    = 24576,     // 64 oc * 8 b * 1024 c = 524288
  OFF_SPART = 548864,    // 64 bz * 32 * 2 = 4096
  OFF_TPART = 552960,    // 64 bz * 2 cs * 4096 = 524288
  OFF_ATTN  = 1077248,   // 8*4096 = 32768
  OFF_S     = 1110016,   // 8
  WS_FLOATS = 1110024
};

__device__ __forceinline__ float breduce_sum(float v, float* red) {
  int t = threadIdx.x;
  red[t] = v; __syncthreads();
  for (int s = 128; s > 0; s >>= 1) { if (t < s) red[t] += red[t + s]; __syncthreads(); }
  float r = red[0]; __syncthreads();
  return r;
}
__device__ __forceinline__ float wave_sum(float v) {
  #pragma unroll
  for (int off = 32; off > 0; off >>= 1) v += __shfl_xor(v, off, 64);
  return v;
}

// ---------------- K1 "head": LN + kv, fused kq partials, Wp prefetch ----------------
// 256 blocks: [0,64) kv k-rows + kq partial; [64,128) kv v-rows; [128,256) prefetch Wp.
__global__ void k_head(const float* __restrict__ ctx, const float* __restrict__ lng,
                       const float* __restrict__ lnb, const float* __restrict__ Wkv,
                       const float* __restrict__ bkv, const float* __restrict__ Wq,
                       const float* __restrict__ Wp,  float* __restrict__ ws) {
  __shared__ __align__(16) float scf[8 * NCTX];   // 24 KB
  __shared__ float sk[8 * 16];                    // this block's 16 k rows x 8 batches
  int t = threadIdx.x, bid = blockIdx.x;
  int wave = t >> 6, lane = t & 63;
  if (bid == 0 && t < NB) ws[OFF_S + t] = 0.f;    // zero softmax sums for k_tail

  if (bid < 128) {
    // LN(ctx) into LDS (each wave handles 2 batches)
    #pragma unroll
    for (int bb = 0; bb < 2; bb++) {
      int b = wave * 2 + bb;
      const float* row = ctx + b * NCTX;
      float v[12];
      float s = 0.f;
      #pragma unroll
      for (int k = 0; k < 12; k++) { v[k] = row[lane + 64 * k]; s += v[k]; }
      float mu = wave_sum(s) * (1.0f / NCTX);
      float s2 = 0.f;
      #pragma unroll
      for (int k = 0; k < 12; k++) { float d = v[k] - mu; s2 = fmaf(d, d, s2); }
      float rstd = rsqrtf(wave_sum(s2) * (1.0f / NCTX) + EPSV);
      #pragma unroll
      for (int k = 0; k < 12; k++) {
        int j = lane + 64 * k;
        scf[b * NCTX + j] = (v[k] - mu) * rstd * lng[j] + lnb[j];
      }
    }
    __syncthreads();
    // kv rows j = bid*16 .. +16  (bid<64 -> k rows; bid in [64,128) -> v rows)
    const float4* W4 = reinterpret_cast<const float4*>(Wkv);
    const float4* sc4 = reinterpret_cast<const float4*>(scf);
    #pragma unroll
    for (int rr = 0; rr < 4; rr++) {
      int j = bid * 16 + wave * 4 + rr;
      float4 wv0 = W4[(size_t)j * 192 + lane];
      float4 wv1 = W4[(size_t)j * 192 + lane + 64];
      float4 wv2 = W4[(size_t)j * 192 + lane + 128];
      #pragma unroll
      for (int b = 0; b < 8; b++) {
        const float4* sb = sc4 + b * 192;
        float4 c0 = sb[lane], c1 = sb[lane + 64], c2 = sb[lane + 128];
        float a = wv0.x*c0.x + wv0.y*c0.y + wv0.z*c0.z + wv0.w*c0.w
                + wv1.x*c1.x + wv1.y*c1.y + wv1.z*c1.z + wv1.w*c1.w
                + wv2.x*c2.x + wv2.y*c2.y + wv2.z*c2.z + wv2.w*c2.w;
        a = wave_sum(a);
        if (lane == 0) {
          ws[OFF_KV + b * 2048 + j] = a + bkv[j];
          if (bid < 64) sk[b * 16 + (wave * 4 + rr)] = a + bkv[j];   // keep k local for kq
        }
      }
    }
    if (bid < 64) {
      // kq partial for o-chunk bid: qp[b][c] += sum_{16 o} k[b][o]*Wq[o,c]
      __syncthreads();
      const float4* Wq4 = reinterpret_cast<const float4*>(Wq);
      float4 acc[8];
      #pragma unroll
      for (int b = 0; b < 8; b++) acc[b] = make_float4(0.f, 0.f, 0.f, 0.f);
      int o0 = bid * 16;
      #pragma unroll 4
      for (int oi = 0; oi < 16; oi++) {
        float4 w = Wq4[(size_t)(o0 + oi) * 256 + t];
        #pragma unroll
        for (int b = 0; b < 8; b++) {
          float kk = sk[b * 16 + oi];
          acc[b].x = fmaf(kk, w.x, acc[b].x);
          acc[b].y = fmaf(kk, w.y, acc[b].y);
          acc[b].z = fmaf(kk, w.z, acc[b].z);
          acc[b].w = fmaf(kk, w.w, acc[b].w);
        }
      }
      float4* qp4 = reinterpret_cast<float4*>(ws + OFF_QP);
      #pragma unroll
      for (int b = 0; b < 8; b++) qp4[(bid * 8 + b) * 256 + t] = acc[b];
    }
  } else {
    // prefetch Wp (4 MB = 262144 float4) into L2/L3 for k_tail's pv
    const float4* Wp4 = reinterpret_cast<const float4*>(Wp);
    int pid = bid - 128;                          // 128 blocks
    float acc = 0.f;
    for (int idx = pid * 256 + t; idx < 262144; idx += 128 * 256) {
      float4 v = Wp4[idx];
      acc += v.x + v.y + v.z + v.w;
    }
    asm volatile("" :: "v"(acc));                 // keep loads alive
  }
}

// ---------------- K2: stream x — GN stats + score partial dots ----------------
// grid (lc=16, cs=2, bz=64), block 256: 2048 blocks.
__global__ void k_pass1(const float* __restrict__ x, const float* __restrict__ gng,
                        float* __restrict__ ws) {
  __shared__ float red[256];
  __shared__ float sw[64];
  __shared__ __align__(16) float4 part[192];
  int t  = threadIdx.x;
  int lc = blockIdx.x;          // 0..15
  int cs = blockIdx.y;          // 0..1
  int bz = blockIdx.z;          // b*8+g
  int b = bz >> 3, g = bz & 7;
  int c0 = g * 128 + cs * 64;
  // combine 64 kq o-chunk partials -> wcoef for our 64 channels
  {
    int cl = t & 63, sp = t >> 6;
    const float* qp = ws + OFF_QP + b * 1024 + c0 + cl;
    float s = 0.f;
    #pragma unroll 4
    for (int oc = sp * 16; oc < sp * 16 + 16; oc++) s += qp[(size_t)oc * 8192];
    red[t] = s;
    __syncthreads();
    if (t < 64) sw[t] = gng[c0 + t] * ((red[t] + red[t + 64]) + (red[t + 128] + red[t + 192]));
    __syncthreads();
  }
  int tl = t & 63, q = t >> 6;
  int l4 = lc * 64 + tl;
  const float4* x4 = reinterpret_cast<const float4*>(x);
  float4 tacc = make_float4(0.f, 0.f, 0.f, 0.f);
  float s1 = 0.f, s2 = 0.f;
  #pragma unroll 4
  for (int ci = q * 16; ci < q * 16 + 16; ci++) {
    float w = sw[ci];
    float4 v = x4[(size_t)(b * NC + c0 + ci) * 1024 + l4];
    tacc.x = fmaf(w, v.x, tacc.x);
    tacc.y = fmaf(w, v.y, tacc.y);
    tacc.z = fmaf(w, v.z, tacc.z);
    tacc.w = fmaf(w, v.w, tacc.w);
    s1 += (v.x + v.y) + (v.z + v.w);
    s2 = fmaf(v.x, v.x, s2); s2 = fmaf(v.y, v.y, s2);
    s2 = fmaf(v.z, v.z, s2); s2 = fmaf(v.w, v.w, s2);
  }
  if (q > 0) part[(q - 1) * 64 + tl] = tacc;
  __syncthreads();
  if (q == 0) {
    float4 p0 = part[tl], p1 = part[64 + tl], p2 = part[128 + tl];
    tacc.x += (p0.x + p1.x) + p2.x;
    tacc.y += (p0.y + p1.y) + p2.y;
    tacc.z += (p0.z + p1.z) + p2.z;
    tacc.w += (p0.w + p1.w) + p2.w;
    reinterpret_cast<float4*>(ws + OFF_TPART)[(size_t)(bz * 2 + cs) * 1024 + l4] = tacc;
  }
  float S1 = breduce_sum(s1, red);
  float S2 = breduce_sum(s2, red);
  if (t == 0) {
    float* sp = ws + OFF_SPART + (bz * 32 + cs * 16 + lc) * 2;
    sp[0] = S1; sp[1] = S2;
  }
}

// ---------------- K3 "tail": scores -> exp + pv (192 blocks) ----------------
// blocks [0,64): scores (8 lc x 8 b); blocks [64,192): pv, 8 rows each (Wp L3-warm).
__global__ void k_tail(const float* __restrict__ Wp, float* __restrict__ ws) {
  __shared__ __align__(16) char smem[32768];
  int t = threadIdx.x, bid = blockIdx.x;
  if (bid < 64) {
    float* srstd = (float*)smem;                 // [8]
    float* red   = (float*)(smem + 1024);        // [256]
    int lc = bid & 7, b = bid >> 3;
    if (t < 8) {
      const float* sp = ws + OFF_SPART + (b * 8 + t) * 64;
      float S1 = 0.f, S2 = 0.f;
      #pragma unroll
      for (int i = 0; i < 32; i++) { S1 += sp[i * 2]; S2 += sp[i * 2 + 1]; }
      const float invN = 1.0f / (128.0f * (float)NL);
      float mu = S1 * invN;
      float var = S2 * invN - mu * mu;
      srstd[t] = rsqrtf(var + EPSV);
    }
    __syncthreads();
    float esum = 0.f;
    #pragma unroll
    for (int r = 0; r < 2; r++) {
      int l = lc * 512 + r * 256 + t;
      float acc = 0.f;
      #pragma unroll
      for (int g = 0; g < 8; g++) {
        const float* tg = ws + OFF_TPART + (size_t)(b * 8 + g) * 8192;
        acc = fmaf(srstd[g], tg[l] + tg[4096 + l], acc);
      }
      float e = expf(fminf(SCALEV * acc, 60.0f));  // per-b consts cancel under softmax
      ws[OFF_ATTN + b * NL + l] = e;
      esum += e;
    }
    float tot = breduce_sum(esum, red);
    if (t == 0) atomicAdd(ws + OFF_S + b, tot);
  } else {
    // pv: 128 blocks x 8 rows; v (all batches) in LDS
    float4* sbuf = (float4*)smem;                // [8][256] = 32 KB
    const float4* kv4 = reinterpret_cast<const float4*>(ws + OFF_KV);
    #pragma unroll
    for (int rep = 0; rep < 8; rep++) {
      int idx = rep * 256 + t;                   // < 2048
      int b = idx >> 8, i = idx & 255;
      sbuf[idx] = kv4[b * 512 + 256 + i];        // v half
    }
    __syncthreads();
    int wave = t >> 6, lane = t & 63;
    const float4* Wp4 = reinterpret_cast<const float4*>(Wp);
    #pragma unroll
    for (int rr = 0; rr < 2; rr++) {
      int o = (bid - 64) * 8 + wave * 2 + rr;    // < 1024 = Wp rows
      float4 w0 = Wp4[(size_t)o * 256 + lane];
      float4 w1 = Wp4[(size_t)o * 256 + lane + 64];
      float4 w2 = Wp4[(size_t)o * 256 + lane + 128];
      float4 w3 = Wp4[(size_t)o * 256 + lane + 192];
      #pragma unroll
      for (int b = 0; b < 8; b++) {
        const float4* sb = sbuf + b * 256;
        float4 c0 = sb[lane], c1 = sb[lane + 64], c2 = sb[lane + 128], c3 = sb[lane + 192];
        float a = w0.x*c0.x + w0.y*c0.y + w0.z*c0.z + w0.w*c0.w
                + w1.x*c1.x + w1.y*c1.y + w1.z*c1.z + w1.w*c1.w
                + w2.x*c2.x + w2.y*c2.y + w2.z*c2.z + w2.w*c2.w
                + w3.x*c3.x + w3.y*c3.y + w3.z*c3.z + w3.w*c3.w;
        a = wave_sum(a);
        if (lane == 0) ws[OFF_PV + b * NC + o] = a;
      }
    }
  }
}

// ---------------- K4: out = x + e*(pv/S) + bp  (NT stores) ----------------
__global__ void k_out(const float* __restrict__ x, const float* __restrict__ bp,
                      const float* __restrict__ ws, float* __restrict__ out) {
  const float4* x4 = reinterpret_cast<const float4*>(x);
  floatx4* o4 = reinterpret_cast<floatx4*>(out);
  const float4* a4 = reinterpret_cast<const float4*>(ws + OFF_ATTN);
  const float* pv = ws + OFF_PV;
  const float* Ss = ws + OFF_S;
  const size_t NT4 = (size_t)NB * NC * NL / 4;  // 8388608
  for (size_t i = (size_t)blockIdx.x * blockDim.x + threadIdx.x; i < NT4;
       i += (size_t)gridDim.x * blockDim.x) {
    int b  = (int)(i >> 20);
    int c  = (int)((i >> 10) & (NC - 1));
    int l4 = (int)(i & 1023);
    float4 xv = x4[i];
    float4 av = a4[(size_t)b * 1024 + l4];
    float p  = pv[b * NC + c] / Ss[b];
    float bb = bp[c];
    floatx4 r;
    r.x = xv.x + fmaf(av.x, p, bb);
    r.y = xv.y + fmaf(av.y, p, bb);
    r.z = xv.z + fmaf(av.z, p, bb);
    r.w = xv.w + fmaf(av.w, p, bb);
    __builtin_nontemporal_store(r, &o4[i]);   // keep x L3-hot
  }
}

extern "C" void kernel_launch(void* const* d_in, const int* in_sizes, int n_in,
                              void* d_out, int out_size, void* d_ws, size_t ws_size,
                              hipStream_t stream) {
  const float* x    = (const float*)d_in[0];
  const float* ctx  = (const float*)d_in[1];
  const float* gng  = (const float*)d_in[2];
  // d_in[3] = gn_beta, d_in[7] = bq : per-b constants, cancel under softmax
  const float* lng  = (const float*)d_in[4];
  const float* lnb  = (const float*)d_in[5];
  const float* Wq   = (const float*)d_in[6];
  const float* Wkv  = (const float*)d_in[8];
  const float* bkv  = (const float*)d_in[9];
  const float* Wp   = (const float*)d_in[10];
  const float* bp   = (const float*)d_in[11];
  float* ws  = (float*)d_ws;
  float* out = (float*)d_out;

  hipLaunchKernelGGL(k_head,   dim3(256),        dim3(256), 0, stream, ctx, lng, lnb, Wkv, bkv, Wq, Wp, ws);
  hipLaunchKernelGGL(k_pass1,  dim3(16, 2, 64),  dim3(256), 0, stream, x, gng, ws);
  hipLaunchKernelGGL(k_tail,   dim3(192),        dim3(256), 0, stream, Wp, ws);
  hipLaunchKernelGGL(k_out,    dim3(2048),       dim3(256), 0, stream, x, bp, ws, out);
}